// Round 10
// baseline (1876.705 us; speedup 1.0000x reference)
//
#include <hip/hip_runtime.h>
#include <hip/hip_bf16.h>

#define N_NODES 50000
#define N_EDGES 600000
#define FEA_DIM 128
#define H_DIM 256
#define N_LAYER 3
#define N_GRAPHS 256
#define LABEL_DIM 2

#define SCAN_NB ((N_NODES + 255) / 256)        // 196
#define GEMM_NB2 ((N_NODES + 63) / 64)         // 782  (128-thr standalone gemm blocks)
#define GEMM_NB4 ((N_NODES + 127) / 128)       // 391  (256-thr fused gemm blocks)
#define EDGE_NB ((N_EDGES + 255) / 256)        // 2344

// ---------------- CSR: degree count ----------------

__global__ __launch_bounds__(256) void k_count(const int* __restrict__ dst, int* __restrict__ counts) {
    int e = blockIdx.x * 256 + threadIdx.x;
    if (e < N_EDGES) atomicAdd(&counts[dst[e]], 1);
}

// ---------------- GEMM per-wave body: H[64 rows, colg] = X @ W column-slice -------
// lane = column; acc[64] covers 64 rows. B(W) loads are lane-consecutive vector
// loads; A(X) loads are wave-uniform -> s_load (SGPR operand in v_fmac). No LDS,
// no barriers. Per-output fmac order: k ascending 0..127 — bitwise stable.

__device__ __forceinline__ void gemm_wave(const float* __restrict__ X, const float* __restrict__ W,
                                          float* __restrict__ H, int M, int row_base, int colg) {
    float acc[64];
#pragma unroll
    for (int r = 0; r < 64; ++r) acc[r] = 0.f;

    for (int kt = 0; kt < 128; kt += 16) {
        // B: W[k][colg], k in [kt, kt+16) — coalesced vector loads, reused by 64 rows
        float bv[16];
#pragma unroll
        for (int j = 0; j < 16; ++j) bv[j] = W[(kt + j) * 128 + colg];
        // rows in pairs: two independent fmac chains saturate VALU issue
#pragma unroll
        for (int r = 0; r < 64; r += 2) {
            int gr = row_base + r;
            if (gr >= M) break;   // M even, row_base even -> pairs never straddle
            const float4* p0 = (const float4*)(X + (size_t)gr * 128 + kt);
            const float4* p1 = (const float4*)(X + (size_t)(gr + 1) * 128 + kt);
            float4 a0 = p0[0], a1 = p0[1], a2 = p0[2], a3 = p0[3];
            float4 c0 = p1[0], c1 = p1[1], c2 = p1[2], c3 = p1[3];
            float xa[16] = {a0.x, a0.y, a0.z, a0.w, a1.x, a1.y, a1.z, a1.w,
                            a2.x, a2.y, a2.z, a2.w, a3.x, a3.y, a3.z, a3.w};
            float xc[16] = {c0.x, c0.y, c0.z, c0.w, c1.x, c1.y, c1.z, c1.w,
                            c2.x, c2.y, c2.z, c2.w, c3.x, c3.y, c3.z, c3.w};
#pragma unroll
            for (int j = 0; j < 16; ++j) {
                acc[r]     += xa[j] * bv[j];
                acc[r + 1] += xc[j] * bv[j];
            }
        }
    }
#pragma unroll
    for (int r = 0; r < 64; ++r) {
        int gr = row_base + r;
        if (gr >= M) break;
        H[(size_t)gr * 128 + colg] = acc[r];   // lane-consecutive: coalesced
    }
}

// Standalone: 128 threads = 2 waves; wave w -> cols [64w, 64w+64); 64 rows/block.
__global__ __launch_bounds__(128) void k_gemm(const float* __restrict__ X, const float* __restrict__ W,
                                              float* __restrict__ H, int M) {
    int wave = threadIdx.x >> 6;
    int lane = threadIdx.x & 63;
    gemm_wave(X, W, H, M, blockIdx.x * 64, wave * 64 + lane);
}

// Fused: blocks [0, GEMM_NB4) run GEMM layer-0 (4 waves = 2 row-groups x 2 col
// halves); blocks [GEMM_NB4, ...) do CSR fill. Independent works, no barriers.
__global__ __launch_bounds__(256) void k_gemm0_fill(const float* __restrict__ X, const float* __restrict__ W,
                                                    float* __restrict__ H,
                                                    const int* __restrict__ src, const int* __restrict__ dst,
                                                    const int* __restrict__ row_ptr, int* __restrict__ cursor,
                                                    int* __restrict__ col) {
    if (blockIdx.x < GEMM_NB4) {
        int wave = threadIdx.x >> 6;
        int lane = threadIdx.x & 63;
        int row_base = blockIdx.x * 128 + (wave >> 1) * 64;
        int colg = (wave & 1) * 64 + lane;
        gemm_wave(X, W, H, N_NODES, row_base, colg);
    } else {
        int e = (blockIdx.x - GEMM_NB4) * 256 + threadIdx.x;
        if (e < N_EDGES) {
            int s = src[e], d = dst[e];
            int p = row_ptr[d] + atomicAdd(&cursor[d], 1);
            col[p] = s;
        }
    }
}

// ---------------- CSR build (scan phases) ----------------

__global__ __launch_bounds__(256) void k_partial(const int* __restrict__ counts, int* __restrict__ partial) {
    int g = blockIdx.x * 256 + threadIdx.x;
    int v = (g < N_NODES) ? counts[g] : 0;
#pragma unroll
    for (int off = 32; off > 0; off >>= 1) v += __shfl_down(v, off);
    __shared__ int ws[4];
    int lane = threadIdx.x & 63, wid = threadIdx.x >> 6;
    if (lane == 0) ws[wid] = v;
    __syncthreads();
    if (threadIdx.x == 0) partial[blockIdx.x] = ws[0] + ws[1] + ws[2] + ws[3];
}

__global__ __launch_bounds__(256) void k_rowptr(const int* __restrict__ counts, const int* __restrict__ partial,
                                                int* __restrict__ row_ptr, float* __restrict__ dinv,
                                                int* __restrict__ cursor) {
    __shared__ int sp[256];
    __shared__ int s[256];
    int tid = threadIdx.x;
    sp[tid] = (tid < SCAN_NB) ? partial[tid] : 0;
    __syncthreads();
#pragma unroll
    for (int off = 1; off < 256; off <<= 1) {
        int t = (tid >= off) ? sp[tid - off] : 0;
        __syncthreads();
        sp[tid] += t;
        __syncthreads();
    }
    int block_off = (blockIdx.x == 0) ? 0 : sp[blockIdx.x - 1];

    int g = blockIdx.x * 256 + tid;
    int c = (g < N_NODES) ? counts[g] : 0;
    s[tid] = c;
    __syncthreads();
#pragma unroll
    for (int off = 1; off < 256; off <<= 1) {
        int t = (tid >= off) ? s[tid - off] : 0;
        __syncthreads();
        s[tid] += t;
        __syncthreads();
    }
    if (g < N_NODES) {
        row_ptr[g] = block_off + s[tid] - c;            // exclusive
        dinv[g] = rsqrtf((float)c + 1.0f);              // +1 = self loop
        cursor[g] = 0;
    }
    if (blockIdx.x == 0 && tid == 0) row_ptr[N_NODES] = sp[SCAN_NB - 1];
}

// ---------------- Aggregation (round-4 variant — measured fastest) ----------
// One wave per node, lane covers feats [2*lane, 2*lane+1] as float2.
// Order: self-loop first, then CSR edges strictly ascending; batch-of-8
// prefetch (issue 8 independent gathers, then accumulate in order).

__global__ __launch_bounds__(256) void k_agg(const float* __restrict__ H, const float* __restrict__ bgl,
                                             const int* __restrict__ row_ptr, const int* __restrict__ col,
                                             const float* __restrict__ dinv,
                                             float* __restrict__ Xo) {
    int wave = (blockIdx.x * 256 + threadIdx.x) >> 6;
    int lane = threadIdx.x & 63;
    if (wave >= N_NODES) return;
    const int i = wave;
    const float2* H2 = (const float2*)H;
    const float di = dinv[i];
    float2 h = H2[(size_t)i * 64 + lane];
    float2 acc;
    acc.x = h.x * di * di;   // self-loop first
    acc.y = h.y * di * di;
    const int p0 = row_ptr[i], p1 = row_ptr[i + 1];
    for (int base = p0; base < p1; base += 64) {
        int m = p1 - base; if (m > 64) m = 64;
        int sc = 0; float wc = 0.f;
        if (lane < m) { sc = col[base + lane]; wc = dinv[sc] * di; }
        for (int j = 0; j < m; j += 8) {
            int cnt = m - j; if (cnt > 8) cnt = 8;
            float2 hbuf[8]; float wbuf[8];
#pragma unroll
            for (int t = 0; t < 8; ++t) {
                if (t < cnt) {
                    int s = __shfl(sc, j + t);
                    wbuf[t] = __shfl(wc, j + t);
                    hbuf[t] = H2[(size_t)s * 64 + lane];
                }
            }
#pragma unroll
            for (int t = 0; t < 8; ++t) {
                if (t < cnt) {
                    acc.x += hbuf[t].x * wbuf[t];
                    acc.y += hbuf[t].y * wbuf[t];
                }
            }
        }
    }
    float2 b = ((const float2*)bgl)[lane];
    float2 o;
    o.x = fmaxf(acc.x + b.x, 0.f);
    o.y = fmaxf(acc.y + b.y, 0.f);
    ((float2*)Xo)[(size_t)i * 64 + lane] = o;
}

// ---------------- Fused mean pool + MLP head ----------------

__global__ __launch_bounds__(256) void k_poolmlp(const float* __restrict__ X, const int* __restrict__ batch,
                                                 const float* __restrict__ w1, const float* __restrict__ b1,
                                                 const float* __restrict__ w2, const float* __restrict__ b2,
                                                 float* __restrict__ out) {
    __shared__ int s_lo, s_hi;
    __shared__ float red[256];
    __shared__ float xs[128];
    __shared__ float hs[256];
    int g = blockIdx.x, tid = threadIdx.x;
    if (tid == 0) {
        int lo = 0, hi = N_NODES;
        while (lo < hi) { int mid = (lo + hi) >> 1; if (batch[mid] < g) lo = mid + 1; else hi = mid; }
        s_lo = lo;
        int lo2 = lo, hi2 = N_NODES;
        while (lo2 < hi2) { int mid = (lo2 + hi2) >> 1; if (batch[mid] < g + 1) lo2 = mid + 1; else hi2 = mid; }
        s_hi = lo2;
    }
    __syncthreads();
    int lo = s_lo, hi = s_hi;
    int f = tid & 127, half = tid >> 7;
    float acc = 0.f;
    for (int r = lo + half; r < hi; r += 2) acc += X[r * 128 + f];
    red[tid] = acc;
    __syncthreads();
    if (tid < 128) {
        int cnt = hi - lo;
        xs[tid] = (red[tid] + red[tid + 128]) / (float)(cnt > 0 ? cnt : 1);
    }
    __syncthreads();
    float a1 = b1[tid];
#pragma unroll 8
    for (int k = 0; k < 128; ++k) a1 += xs[k] * w1[k * H_DIM + tid];
    hs[tid] = fmaxf(a1, 0.f);
    __syncthreads();
    int j = tid >> 7, t2 = tid & 127;
    float p = hs[t2] * w2[t2 * LABEL_DIM + j] + hs[t2 + 128] * w2[(t2 + 128) * LABEL_DIM + j];
    red[tid] = p;
    __syncthreads();
    for (int s2 = 64; s2 > 0; s2 >>= 1) {
        if (t2 < s2) red[tid] += red[tid + s2];
        __syncthreads();
    }
    if (t2 == 0) out[g * LABEL_DIM + j] = red[tid] + b2[j];
}

// ---------------- launch ----------------

extern "C" void kernel_launch(void* const* d_in, const int* in_sizes, int n_in,
                              void* d_out, int out_size, void* d_ws, size_t ws_size,
                              hipStream_t stream) {
    const float* x   = (const float*)d_in[0];
    const float* Wg  = (const float*)d_in[1];
    const float* bg  = (const float*)d_in[2];
    const float* w1  = (const float*)d_in[3];
    const float* b1  = (const float*)d_in[4];
    const float* w2  = (const float*)d_in[5];
    const float* b2  = (const float*)d_in[6];
    const int* eidx  = (const int*)d_in[7];
    const int* batch = (const int*)d_in[8];
    float* out = (float*)d_out;

    const int* src = eidx;
    const int* dst = eidx + N_EDGES;

    char* ws = (char*)d_ws;
    size_t off = 0;
    float* A = (float*)(ws + off); off += (size_t)N_NODES * FEA_DIM * 4;
    float* B = (float*)(ws + off); off += (size_t)N_NODES * FEA_DIM * 4;
    int*   col = (int*)(ws + off); off += (size_t)N_EDGES * 4;
    int*   row_ptr = (int*)(ws + off); off += 200704;
    int*   cursor  = (int*)(ws + off); off += 200704;
    int*   counts  = (int*)(ws + off); off += 200704;
    float* dinv    = (float*)(ws + off); off += 200704;
    int*   partial = (int*)(ws + off); off += 4096;

    hipMemsetAsync(counts, 0, 200704, stream);
    k_count<<<EDGE_NB, 256, 0, stream>>>(dst, counts);
    k_partial<<<SCAN_NB, 256, 0, stream>>>(counts, partial);
    k_rowptr<<<SCAN_NB, 256, 0, stream>>>(counts, partial, row_ptr, dinv, cursor);
    // gemm layer-0 fused with CSR fill (independent works)
    k_gemm0_fill<<<GEMM_NB4 + EDGE_NB, 256, 0, stream>>>(x, Wg, B, src, dst, row_ptr, cursor, col);

    k_agg<<<(N_NODES + 3) / 4, 256, 0, stream>>>(B, bg + 0 * FEA_DIM, row_ptr, col, dinv, A);
    for (int l = 1; l < N_LAYER; ++l) {
        k_gemm<<<GEMM_NB2, 128, 0, stream>>>(A, Wg + (size_t)l * FEA_DIM * FEA_DIM, B, N_NODES);
        k_agg<<<(N_NODES + 3) / 4, 256, 0, stream>>>(B, bg + (size_t)l * FEA_DIM, row_ptr, col, dinv, A);
    }
    k_poolmlp<<<N_GRAPHS, 256, 0, stream>>>(A, batch, w1, b1, w2, b2, out);
}

// Round 11
// 399.956 us; speedup vs baseline: 4.6923x; 4.6923x over previous
//
#include <hip/hip_runtime.h>
#include <hip/hip_bf16.h>

#define N_NODES 50000
#define N_EDGES 600000
#define FEA_DIM 128
#define H_DIM 256
#define N_LAYER 3
#define N_GRAPHS 256
#define LABEL_DIM 2

#define SCAN_NB ((N_NODES + 255) / 256)        // 196
#define GEMM_NB ((N_NODES + 63) / 64)          // 782
#define EDGE_NB ((N_EDGES + 255) / 256)        // 2344

// ---------------- CSR: degree count ----------------

__global__ __launch_bounds__(256) void k_count(const int* __restrict__ dst, int* __restrict__ counts) {
    int e = blockIdx.x * 256 + threadIdx.x;
    if (e < N_EDGES) atomicAdd(&counts[dst[e]], 1);
}

// ---------------- GEMM body (round-9 proven): BM=64, BK=32, 256 thr, 4x8 ----
// A staged transposed [k][m]. Per-output fmac order: k ascending 0..127.

__device__ __forceinline__ void gemm_body(const float* __restrict__ X, const float* __restrict__ W,
                                          float* __restrict__ H, int M, int tile) {
    __shared__ float a_s[32][68];
    __shared__ float b_s[32][128];
    const int tid = threadIdx.x;
    const int row_g = tid >> 4;
    const int col_g = tid & 15;
    const int row_base = tile * 64;
    float acc[4][8] = {};

    for (int kt = 0; kt < 4; ++kt) {
        const int k0 = kt * 32;
#pragma unroll
        for (int j = 0; j < 2; ++j) {
            int id = tid + j * 256;
            int m = id >> 3;
            int kq = (id & 7) << 2;
            float4 v = make_float4(0.f, 0.f, 0.f, 0.f);
            int gr = row_base + m;
            if (gr < M) v = *(const float4*)(X + gr * 128 + k0 + kq);
            a_s[kq + 0][m] = v.x; a_s[kq + 1][m] = v.y;
            a_s[kq + 2][m] = v.z; a_s[kq + 3][m] = v.w;
        }
#pragma unroll
        for (int j = 0; j < 4; ++j) {
            int id = tid + j * 256;
            int k = id >> 5;
            int n = (id & 31) << 2;
            *(float4*)(&b_s[k][n]) = *(const float4*)(W + (k0 + k) * 128 + n);
        }
        __syncthreads();
#pragma unroll 8
        for (int k = 0; k < 32; ++k) {
            float4 a0 = *(const float4*)(&a_s[k][row_g * 4]);
            float4 b0 = *(const float4*)(&b_s[k][col_g * 4]);
            float4 b1 = *(const float4*)(&b_s[k][64 + col_g * 4]);
            float av[4] = {a0.x, a0.y, a0.z, a0.w};
            float bv[8] = {b0.x, b0.y, b0.z, b0.w, b1.x, b1.y, b1.z, b1.w};
#pragma unroll
            for (int i = 0; i < 4; ++i)
#pragma unroll
                for (int jj = 0; jj < 8; ++jj) acc[i][jj] += av[i] * bv[jj];
        }
        __syncthreads();
    }
#pragma unroll
    for (int i = 0; i < 4; ++i) {
        int gr = row_base + row_g * 4 + i;
        if (gr < M) {
            float4 o0 = {acc[i][0], acc[i][1], acc[i][2], acc[i][3]};
            float4 o1 = {acc[i][4], acc[i][5], acc[i][6], acc[i][7]};
            *(float4*)(H + gr * 128 + col_g * 4) = o0;
            *(float4*)(H + gr * 128 + 64 + col_g * 4) = o1;
        }
    }
}

// ---------------- Standalone GEMM: BM=64, 128 threads, 8x8 micro-tile -------
// Per k-step per lane: 64 FMA vs 4 ds_read_b128 -> VALU-bound (the 4x8 variant
// was LDS-bound at 32 FMA per 48B of LDS reads). VGPR ~110 (no spill),
// LDS 25 KB -> 6 blocks/CU. Per-output fmac order: k ascending — bitwise stable.

__global__ __launch_bounds__(128) void k_gemm8(const float* __restrict__ X, const float* __restrict__ W,
                                               float* __restrict__ H, int M) {
    __shared__ float a_s[32][68];
    __shared__ float b_s[32][128];
    const int tid = threadIdx.x;        // 0..127
    const int row_g = tid >> 4;         // 0..7  -> rows row_g*8 .. +8
    const int col_g = tid & 15;         // 0..15 -> cols col_g*4 and 64+col_g*4
    const int row_base = blockIdx.x * 64;
    float acc[8][8] = {};

    for (int kt = 0; kt < 4; ++kt) {
        const int k0 = kt * 32;
        // A tile: 64 rows x 32 k = 512 float4 -> 4 per thread (transposed store)
#pragma unroll
        for (int j = 0; j < 4; ++j) {
            int id = tid + j * 128;
            int m = id >> 3;
            int kq = (id & 7) << 2;
            float4 v = make_float4(0.f, 0.f, 0.f, 0.f);
            int gr = row_base + m;
            if (gr < M) v = *(const float4*)(X + gr * 128 + k0 + kq);
            a_s[kq + 0][m] = v.x; a_s[kq + 1][m] = v.y;
            a_s[kq + 2][m] = v.z; a_s[kq + 3][m] = v.w;
        }
        // B tile: 32 k x 128 n = 1024 float4 -> 8 per thread
#pragma unroll
        for (int j = 0; j < 8; ++j) {
            int id = tid + j * 128;
            int k = id >> 5;
            int n = (id & 31) << 2;
            *(float4*)(&b_s[k][n]) = *(const float4*)(W + (k0 + k) * 128 + n);
        }
        __syncthreads();
#pragma unroll 4
        for (int k = 0; k < 32; ++k) {
            float4 a0 = *(const float4*)(&a_s[k][row_g * 8]);
            float4 a1 = *(const float4*)(&a_s[k][row_g * 8 + 4]);
            float4 b0 = *(const float4*)(&b_s[k][col_g * 4]);
            float4 b1 = *(const float4*)(&b_s[k][64 + col_g * 4]);
            float av[8] = {a0.x, a0.y, a0.z, a0.w, a1.x, a1.y, a1.z, a1.w};
            float bv[8] = {b0.x, b0.y, b0.z, b0.w, b1.x, b1.y, b1.z, b1.w};
#pragma unroll
            for (int i = 0; i < 8; ++i)
#pragma unroll
                for (int jj = 0; jj < 8; ++jj) acc[i][jj] += av[i] * bv[jj];
        }
        __syncthreads();
    }
#pragma unroll
    for (int i = 0; i < 8; ++i) {
        int gr = row_base + row_g * 8 + i;
        if (gr < M) {
            float4 o0 = {acc[i][0], acc[i][1], acc[i][2], acc[i][3]};
            float4 o1 = {acc[i][4], acc[i][5], acc[i][6], acc[i][7]};
            *(float4*)(H + gr * 128 + col_g * 4) = o0;
            *(float4*)(H + gr * 128 + 64 + col_g * 4) = o1;
        }
    }
}

// Fused: blocks [0, GEMM_NB) run GEMM layer-0 tiles; blocks [GEMM_NB, ...) do
// CSR fill (needs row_ptr/cursor from k_rowptr; gemm0 doesn't). Independent works.
__global__ __launch_bounds__(256) void k_gemm0_fill(const float* __restrict__ X, const float* __restrict__ W,
                                                    float* __restrict__ H,
                                                    const int* __restrict__ src, const int* __restrict__ dst,
                                                    const int* __restrict__ row_ptr, int* __restrict__ cursor,
                                                    int* __restrict__ col) {
    if (blockIdx.x < GEMM_NB) {
        gemm_body(X, W, H, N_NODES, blockIdx.x);
    } else {
        int e = (blockIdx.x - GEMM_NB) * 256 + threadIdx.x;
        if (e < N_EDGES) {
            int s = src[e], d = dst[e];
            int p = row_ptr[d] + atomicAdd(&cursor[d], 1);
            col[p] = s;
        }
    }
}

// ---------------- CSR build (scan phases) ----------------

__global__ __launch_bounds__(256) void k_partial(const int* __restrict__ counts, int* __restrict__ partial) {
    int g = blockIdx.x * 256 + threadIdx.x;
    int v = (g < N_NODES) ? counts[g] : 0;
#pragma unroll
    for (int off = 32; off > 0; off >>= 1) v += __shfl_down(v, off);
    __shared__ int ws[4];
    int lane = threadIdx.x & 63, wid = threadIdx.x >> 6;
    if (lane == 0) ws[wid] = v;
    __syncthreads();
    if (threadIdx.x == 0) partial[blockIdx.x] = ws[0] + ws[1] + ws[2] + ws[3];
}

__global__ __launch_bounds__(256) void k_rowptr(const int* __restrict__ counts, const int* __restrict__ partial,
                                                int* __restrict__ row_ptr, float* __restrict__ dinv,
                                                int* __restrict__ cursor) {
    __shared__ int sp[256];
    __shared__ int s[256];
    int tid = threadIdx.x;
    sp[tid] = (tid < SCAN_NB) ? partial[tid] : 0;
    __syncthreads();
#pragma unroll
    for (int off = 1; off < 256; off <<= 1) {
        int t = (tid >= off) ? sp[tid - off] : 0;
        __syncthreads();
        sp[tid] += t;
        __syncthreads();
    }
    int block_off = (blockIdx.x == 0) ? 0 : sp[blockIdx.x - 1];

    int g = blockIdx.x * 256 + tid;
    int c = (g < N_NODES) ? counts[g] : 0;
    s[tid] = c;
    __syncthreads();
#pragma unroll
    for (int off = 1; off < 256; off <<= 1) {
        int t = (tid >= off) ? s[tid - off] : 0;
        __syncthreads();
        s[tid] += t;
        __syncthreads();
    }
    if (g < N_NODES) {
        row_ptr[g] = block_off + s[tid] - c;            // exclusive
        dinv[g] = rsqrtf((float)c + 1.0f);              // +1 = self loop
        cursor[g] = 0;
    }
    if (blockIdx.x == 0 && tid == 0) row_ptr[N_NODES] = sp[SCAN_NB - 1];
}

// ---------------- Aggregation (round-4 variant — measured fastest) ----------
// One wave per node, lane covers feats [2*lane, 2*lane+1] as float2.
// Order: self-loop first, then CSR edges strictly ascending; batch-of-8
// prefetch (issue 8 independent gathers, then accumulate in order).

__global__ __launch_bounds__(256) void k_agg(const float* __restrict__ H, const float* __restrict__ bgl,
                                             const int* __restrict__ row_ptr, const int* __restrict__ col,
                                             const float* __restrict__ dinv,
                                             float* __restrict__ Xo) {
    int wave = (blockIdx.x * 256 + threadIdx.x) >> 6;
    int lane = threadIdx.x & 63;
    if (wave >= N_NODES) return;
    const int i = wave;
    const float2* H2 = (const float2*)H;
    const float di = dinv[i];
    float2 h = H2[(size_t)i * 64 + lane];
    float2 acc;
    acc.x = h.x * di * di;   // self-loop first
    acc.y = h.y * di * di;
    const int p0 = row_ptr[i], p1 = row_ptr[i + 1];
    for (int base = p0; base < p1; base += 64) {
        int m = p1 - base; if (m > 64) m = 64;
        int sc = 0; float wc = 0.f;
        if (lane < m) { sc = col[base + lane]; wc = dinv[sc] * di; }
        for (int j = 0; j < m; j += 8) {
            int cnt = m - j; if (cnt > 8) cnt = 8;
            float2 hbuf[8]; float wbuf[8];
#pragma unroll
            for (int t = 0; t < 8; ++t) {
                if (t < cnt) {
                    int s = __shfl(sc, j + t);
                    wbuf[t] = __shfl(wc, j + t);
                    hbuf[t] = H2[(size_t)s * 64 + lane];
                }
            }
#pragma unroll
            for (int t = 0; t < 8; ++t) {
                if (t < cnt) {
                    acc.x += hbuf[t].x * wbuf[t];
                    acc.y += hbuf[t].y * wbuf[t];
                }
            }
        }
    }
    float2 b = ((const float2*)bgl)[lane];
    float2 o;
    o.x = fmaxf(acc.x + b.x, 0.f);
    o.y = fmaxf(acc.y + b.y, 0.f);
    ((float2*)Xo)[(size_t)i * 64 + lane] = o;
}

// ---------------- Fused mean pool + MLP head ----------------

__global__ __launch_bounds__(256) void k_poolmlp(const float* __restrict__ X, const int* __restrict__ batch,
                                                 const float* __restrict__ w1, const float* __restrict__ b1,
                                                 const float* __restrict__ w2, const float* __restrict__ b2,
                                                 float* __restrict__ out) {
    __shared__ int s_lo, s_hi;
    __shared__ float red[256];
    __shared__ float xs[128];
    __shared__ float hs[256];
    int g = blockIdx.x, tid = threadIdx.x;
    if (tid == 0) {
        int lo = 0, hi = N_NODES;
        while (lo < hi) { int mid = (lo + hi) >> 1; if (batch[mid] < g) lo = mid + 1; else hi = mid; }
        s_lo = lo;
        int lo2 = lo, hi2 = N_NODES;
        while (lo2 < hi2) { int mid = (lo2 + hi2) >> 1; if (batch[mid] < g + 1) lo2 = mid + 1; else hi2 = mid; }
        s_hi = lo2;
    }
    __syncthreads();
    int lo = s_lo, hi = s_hi;
    int f = tid & 127, half = tid >> 7;
    float acc = 0.f;
    for (int r = lo + half; r < hi; r += 2) acc += X[r * 128 + f];
    red[tid] = acc;
    __syncthreads();
    if (tid < 128) {
        int cnt = hi - lo;
        xs[tid] = (red[tid] + red[tid + 128]) / (float)(cnt > 0 ? cnt : 1);
    }
    __syncthreads();
    float a1 = b1[tid];
#pragma unroll 8
    for (int k = 0; k < 128; ++k) a1 += xs[k] * w1[k * H_DIM + tid];
    hs[tid] = fmaxf(a1, 0.f);
    __syncthreads();
    int j = tid >> 7, t2 = tid & 127;
    float p = hs[t2] * w2[t2 * LABEL_DIM + j] + hs[t2 + 128] * w2[(t2 + 128) * LABEL_DIM + j];
    red[tid] = p;
    __syncthreads();
    for (int s2 = 64; s2 > 0; s2 >>= 1) {
        if (t2 < s2) red[tid] += red[tid + s2];
        __syncthreads();
    }
    if (t2 == 0) out[g * LABEL_DIM + j] = red[tid] + b2[j];
}

// ---------------- launch ----------------

extern "C" void kernel_launch(void* const* d_in, const int* in_sizes, int n_in,
                              void* d_out, int out_size, void* d_ws, size_t ws_size,
                              hipStream_t stream) {
    const float* x   = (const float*)d_in[0];
    const float* Wg  = (const float*)d_in[1];
    const float* bg  = (const float*)d_in[2];
    const float* w1  = (const float*)d_in[3];
    const float* b1  = (const float*)d_in[4];
    const float* w2  = (const float*)d_in[5];
    const float* b2  = (const float*)d_in[6];
    const int* eidx  = (const int*)d_in[7];
    const int* batch = (const int*)d_in[8];
    float* out = (float*)d_out;

    const int* src = eidx;
    const int* dst = eidx + N_EDGES;

    char* ws = (char*)d_ws;
    size_t off = 0;
    float* A = (float*)(ws + off); off += (size_t)N_NODES * FEA_DIM * 4;
    float* B = (float*)(ws + off); off += (size_t)N_NODES * FEA_DIM * 4;
    int*   col = (int*)(ws + off); off += (size_t)N_EDGES * 4;
    int*   row_ptr = (int*)(ws + off); off += 200704;
    int*   cursor  = (int*)(ws + off); off += 200704;
    int*   counts  = (int*)(ws + off); off += 200704;
    float* dinv    = (float*)(ws + off); off += 200704;
    int*   partial = (int*)(ws + off); off += 4096;

    hipMemsetAsync(counts, 0, 200704, stream);
    k_count<<<EDGE_NB, 256, 0, stream>>>(dst, counts);
    k_partial<<<SCAN_NB, 256, 0, stream>>>(counts, partial);
    k_rowptr<<<SCAN_NB, 256, 0, stream>>>(counts, partial, row_ptr, dinv, cursor);
    // gemm layer-0 fused with CSR fill (independent works)
    k_gemm0_fill<<<GEMM_NB + EDGE_NB, 256, 0, stream>>>(x, Wg, B, src, dst, row_ptr, cursor, col);

    k_agg<<<(N_NODES + 3) / 4, 256, 0, stream>>>(B, bg + 0 * FEA_DIM, row_ptr, col, dinv, A);
    for (int l = 1; l < N_LAYER; ++l) {
        k_gemm8<<<GEMM_NB, 128, 0, stream>>>(A, Wg + (size_t)l * FEA_DIM * FEA_DIM, B, N_NODES);
        k_agg<<<(N_NODES + 3) / 4, 256, 0, stream>>>(B, bg + (size_t)l * FEA_DIM, row_ptr, col, dinv, A);
    }
    k_poolmlp<<<N_GRAPHS, 256, 0, stream>>>(A, batch, w1, b1, w2, b2, out);
}

// Round 12
// 368.920 us; speedup vs baseline: 5.0870x; 1.0841x over previous
//
#include <hip/hip_runtime.h>
#include <hip/hip_bf16.h>

#define N_NODES 50000
#define N_EDGES 600000
#define FEA_DIM 128
#define H_DIM 256
#define N_LAYER 3
#define N_GRAPHS 256
#define LABEL_DIM 2

#define SCAN_NB ((N_NODES + 255) / 256)        // 196
#define GEMM_NB ((N_NODES + 63) / 64)          // 782
#define EDGE_NB ((N_EDGES + 255) / 256)        // 2344
#define AGG_NB (((N_NODES + 7) / 8) * 2)       // 12500: 2 feature-halves x 6250 node-groups

// ---------------- CSR: degree count ----------------

__global__ __launch_bounds__(256) void k_count(const int* __restrict__ dst, int* __restrict__ counts) {
    int e = blockIdx.x * 256 + threadIdx.x;
    if (e < N_EDGES) atomicAdd(&counts[dst[e]], 1);
}

// ---------------- GEMM body (round-9 proven): BM=64, BK=32, 256 thr, 4x8 ----
// A staged transposed [k][m]. Per-output fmac order: k ascending 0..127.

__device__ __forceinline__ void gemm_body(const float* __restrict__ X, const float* __restrict__ W,
                                          float* __restrict__ H, int M, int tile) {
    __shared__ float a_s[32][68];
    __shared__ float b_s[32][128];
    const int tid = threadIdx.x;
    const int row_g = tid >> 4;
    const int col_g = tid & 15;
    const int row_base = tile * 64;
    float acc[4][8] = {};

    for (int kt = 0; kt < 4; ++kt) {
        const int k0 = kt * 32;
#pragma unroll
        for (int j = 0; j < 2; ++j) {
            int id = tid + j * 256;
            int m = id >> 3;
            int kq = (id & 7) << 2;
            float4 v = make_float4(0.f, 0.f, 0.f, 0.f);
            int gr = row_base + m;
            if (gr < M) v = *(const float4*)(X + gr * 128 + k0 + kq);
            a_s[kq + 0][m] = v.x; a_s[kq + 1][m] = v.y;
            a_s[kq + 2][m] = v.z; a_s[kq + 3][m] = v.w;
        }
#pragma unroll
        for (int j = 0; j < 4; ++j) {
            int id = tid + j * 256;
            int k = id >> 5;
            int n = (id & 31) << 2;
            *(float4*)(&b_s[k][n]) = *(const float4*)(W + (k0 + k) * 128 + n);
        }
        __syncthreads();
#pragma unroll 8
        for (int k = 0; k < 32; ++k) {
            float4 a0 = *(const float4*)(&a_s[k][row_g * 4]);
            float4 b0 = *(const float4*)(&b_s[k][col_g * 4]);
            float4 b1 = *(const float4*)(&b_s[k][64 + col_g * 4]);
            float av[4] = {a0.x, a0.y, a0.z, a0.w};
            float bv[8] = {b0.x, b0.y, b0.z, b0.w, b1.x, b1.y, b1.z, b1.w};
#pragma unroll
            for (int i = 0; i < 4; ++i)
#pragma unroll
                for (int jj = 0; jj < 8; ++jj) acc[i][jj] += av[i] * bv[jj];
        }
        __syncthreads();
    }
#pragma unroll
    for (int i = 0; i < 4; ++i) {
        int gr = row_base + row_g * 4 + i;
        if (gr < M) {
            float4 o0 = {acc[i][0], acc[i][1], acc[i][2], acc[i][3]};
            float4 o1 = {acc[i][4], acc[i][5], acc[i][6], acc[i][7]};
            *(float4*)(H + gr * 128 + col_g * 4) = o0;
            *(float4*)(H + gr * 128 + 64 + col_g * 4) = o1;
        }
    }
}

__global__ __launch_bounds__(256) void k_gemm(const float* __restrict__ X, const float* __restrict__ W,
                                              float* __restrict__ H, int M) {
    gemm_body(X, W, H, M, blockIdx.x);
}

// Fused: blocks [0, GEMM_NB) run GEMM layer-0 tiles; blocks [GEMM_NB, ...) do
// CSR fill. Independent works.
__global__ __launch_bounds__(256) void k_gemm0_fill(const float* __restrict__ X, const float* __restrict__ W,
                                                    float* __restrict__ H,
                                                    const int* __restrict__ src, const int* __restrict__ dst,
                                                    const int* __restrict__ row_ptr, int* __restrict__ cursor,
                                                    int* __restrict__ col) {
    if (blockIdx.x < GEMM_NB) {
        gemm_body(X, W, H, N_NODES, blockIdx.x);
    } else {
        int e = (blockIdx.x - GEMM_NB) * 256 + threadIdx.x;
        if (e < N_EDGES) {
            int s = src[e], d = dst[e];
            int p = row_ptr[d] + atomicAdd(&cursor[d], 1);
            col[p] = s;
        }
    }
}

// ---------------- CSR build (scan phases) ----------------

__global__ __launch_bounds__(256) void k_partial(const int* __restrict__ counts, int* __restrict__ partial) {
    int g = blockIdx.x * 256 + threadIdx.x;
    int v = (g < N_NODES) ? counts[g] : 0;
#pragma unroll
    for (int off = 32; off > 0; off >>= 1) v += __shfl_down(v, off);
    __shared__ int ws[4];
    int lane = threadIdx.x & 63, wid = threadIdx.x >> 6;
    if (lane == 0) ws[wid] = v;
    __syncthreads();
    if (threadIdx.x == 0) partial[blockIdx.x] = ws[0] + ws[1] + ws[2] + ws[3];
}

__global__ __launch_bounds__(256) void k_rowptr(const int* __restrict__ counts, const int* __restrict__ partial,
                                                int* __restrict__ row_ptr, float* __restrict__ dinv,
                                                int* __restrict__ cursor) {
    __shared__ int sp[256];
    __shared__ int s[256];
    int tid = threadIdx.x;
    sp[tid] = (tid < SCAN_NB) ? partial[tid] : 0;
    __syncthreads();
#pragma unroll
    for (int off = 1; off < 256; off <<= 1) {
        int t = (tid >= off) ? sp[tid - off] : 0;
        __syncthreads();
        sp[tid] += t;
        __syncthreads();
    }
    int block_off = (blockIdx.x == 0) ? 0 : sp[blockIdx.x - 1];

    int g = blockIdx.x * 256 + tid;
    int c = (g < N_NODES) ? counts[g] : 0;
    s[tid] = c;
    __syncthreads();
#pragma unroll
    for (int off = 1; off < 256; off <<= 1) {
        int t = (tid >= off) ? s[tid - off] : 0;
        __syncthreads();
        s[tid] += t;
        __syncthreads();
    }
    if (g < N_NODES) {
        row_ptr[g] = block_off + s[tid] - c;            // exclusive
        dinv[g] = rsqrtf((float)c + 1.0f);              // +1 = self loop
        cursor[g] = 0;
    }
    if (blockIdx.x == 0 && tid == 0) row_ptr[N_NODES] = sp[SCAN_NB - 1];
}

// ---------------- Aggregation: XCD-aware feature split ----------------
// blockIdx%8 -> XCD (round-robin heuristic), so feature-half = blockIdx&1 puts
// half 0 on even XCDs, half 1 on odd: each XCD's L2 only ever caches 2 of the
// 4 cache lines per H row -> per-XCD compulsory-miss traffic drops ~145->~98MB.
// Block: 8 half-wave units x 32 lanes; unit = one node's 64-feature half
// (float2/lane). Per-output fmac order unchanged: self-loop, then CSR edges
// strictly ascending (batch-of-8 prefetch) — bitwise identical to round 9.

__global__ __launch_bounds__(256) void k_agg(const float* __restrict__ H, const float* __restrict__ bgl,
                                             const int* __restrict__ row_ptr, const int* __restrict__ col,
                                             const float* __restrict__ dinv,
                                             float* __restrict__ Xo) {
    const int b = blockIdx.x;
    const int half = b & 1;                       // feature half (XCD parity)
    const int unit = threadIdx.x >> 5;            // 0..7
    const int fl = threadIdx.x & 31;
    const int i = (b >> 1) * 8 + unit;            // node id
    if (i >= N_NODES) return;
    const int fo = half * 32 + fl;                // float2 index within the row
    const float2* H2 = (const float2*)H;
    const float di = dinv[i];
    float2 h = H2[(size_t)i * 64 + fo];
    float2 acc;
    acc.x = h.x * di * di;   // self-loop first
    acc.y = h.y * di * di;
    const int p0 = row_ptr[i], p1 = row_ptr[i + 1];
    for (int base = p0; base < p1; base += 32) {
        int m = p1 - base; if (m > 32) m = 32;
        int sc = 0; float wc = 0.f;
        if (fl < m) { sc = col[base + fl]; wc = dinv[sc] * di; }
        for (int j = 0; j < m; j += 8) {
            int cnt = m - j; if (cnt > 8) cnt = 8;
            float2 hbuf[8]; float wbuf[8];
#pragma unroll
            for (int t = 0; t < 8; ++t) {
                if (t < cnt) {
                    int s = __shfl(sc, j + t, 32);
                    wbuf[t] = __shfl(wc, j + t, 32);
                    hbuf[t] = H2[(size_t)s * 64 + fo];
                }
            }
#pragma unroll
            for (int t = 0; t < 8; ++t) {
                if (t < cnt) {
                    acc.x += hbuf[t].x * wbuf[t];
                    acc.y += hbuf[t].y * wbuf[t];
                }
            }
        }
    }
    float2 bb = ((const float2*)bgl)[fo];
    float2 o;
    o.x = fmaxf(acc.x + bb.x, 0.f);
    o.y = fmaxf(acc.y + bb.y, 0.f);
    ((float2*)Xo)[(size_t)i * 64 + fo] = o;
}

// ---------------- Fused mean pool + MLP head ----------------

__global__ __launch_bounds__(256) void k_poolmlp(const float* __restrict__ X, const int* __restrict__ batch,
                                                 const float* __restrict__ w1, const float* __restrict__ b1,
                                                 const float* __restrict__ w2, const float* __restrict__ b2,
                                                 float* __restrict__ out) {
    __shared__ int s_lo, s_hi;
    __shared__ float red[256];
    __shared__ float xs[128];
    __shared__ float hs[256];
    int g = blockIdx.x, tid = threadIdx.x;
    if (tid == 0) {
        int lo = 0, hi = N_NODES;
        while (lo < hi) { int mid = (lo + hi) >> 1; if (batch[mid] < g) lo = mid + 1; else hi = mid; }
        s_lo = lo;
        int lo2 = lo, hi2 = N_NODES;
        while (lo2 < hi2) { int mid = (lo2 + hi2) >> 1; if (batch[mid] < g + 1) lo2 = mid + 1; else hi2 = mid; }
        s_hi = lo2;
    }
    __syncthreads();
    int lo = s_lo, hi = s_hi;
    int f = tid & 127, half = tid >> 7;
    float acc = 0.f;
    for (int r = lo + half; r < hi; r += 2) acc += X[r * 128 + f];
    red[tid] = acc;
    __syncthreads();
    if (tid < 128) {
        int cnt = hi - lo;
        xs[tid] = (red[tid] + red[tid + 128]) / (float)(cnt > 0 ? cnt : 1);
    }
    __syncthreads();
    float a1 = b1[tid];
#pragma unroll 8
    for (int k = 0; k < 128; ++k) a1 += xs[k] * w1[k * H_DIM + tid];
    hs[tid] = fmaxf(a1, 0.f);
    __syncthreads();
    int j = tid >> 7, t2 = tid & 127;
    float p = hs[t2] * w2[t2 * LABEL_DIM + j] + hs[t2 + 128] * w2[(t2 + 128) * LABEL_DIM + j];
    red[tid] = p;
    __syncthreads();
    for (int s2 = 64; s2 > 0; s2 >>= 1) {
        if (t2 < s2) red[tid] += red[tid + s2];
        __syncthreads();
    }
    if (t2 == 0) out[g * LABEL_DIM + j] = red[tid] + b2[j];
}

// ---------------- launch ----------------

extern "C" void kernel_launch(void* const* d_in, const int* in_sizes, int n_in,
                              void* d_out, int out_size, void* d_ws, size_t ws_size,
                              hipStream_t stream) {
    const float* x   = (const float*)d_in[0];
    const float* Wg  = (const float*)d_in[1];
    const float* bg  = (const float*)d_in[2];
    const float* w1  = (const float*)d_in[3];
    const float* b1  = (const float*)d_in[4];
    const float* w2  = (const float*)d_in[5];
    const float* b2  = (const float*)d_in[6];
    const int* eidx  = (const int*)d_in[7];
    const int* batch = (const int*)d_in[8];
    float* out = (float*)d_out;

    const int* src = eidx;
    const int* dst = eidx + N_EDGES;

    char* ws = (char*)d_ws;
    size_t off = 0;
    float* A = (float*)(ws + off); off += (size_t)N_NODES * FEA_DIM * 4;
    float* B = (float*)(ws + off); off += (size_t)N_NODES * FEA_DIM * 4;
    int*   col = (int*)(ws + off); off += (size_t)N_EDGES * 4;
    int*   row_ptr = (int*)(ws + off); off += 200704;
    int*   cursor  = (int*)(ws + off); off += 200704;
    int*   counts  = (int*)(ws + off); off += 200704;
    float* dinv    = (float*)(ws + off); off += 200704;
    int*   partial = (int*)(ws + off); off += 4096;

    hipMemsetAsync(counts, 0, 200704, stream);
    k_count<<<EDGE_NB, 256, 0, stream>>>(dst, counts);
    k_partial<<<SCAN_NB, 256, 0, stream>>>(counts, partial);
    k_rowptr<<<SCAN_NB, 256, 0, stream>>>(counts, partial, row_ptr, dinv, cursor);
    // gemm layer-0 fused with CSR fill (independent works)
    k_gemm0_fill<<<GEMM_NB + EDGE_NB, 256, 0, stream>>>(x, Wg, B, src, dst, row_ptr, cursor, col);

    k_agg<<<AGG_NB, 256, 0, stream>>>(B, bg + 0 * FEA_DIM, row_ptr, col, dinv, A);
    for (int l = 1; l < N_LAYER; ++l) {
        k_gemm<<<GEMM_NB, 256, 0, stream>>>(A, Wg + (size_t)l * FEA_DIM * FEA_DIM, B, N_NODES);
        k_agg<<<AGG_NB, 256, 0, stream>>>(B, bg + (size_t)l * FEA_DIM, row_ptr, col, dinv, A);
    }
    k_poolmlp<<<N_GRAPHS, 256, 0, stream>>>(A, batch, w1, b1, w2, b2, out);
}